// Round 6
// baseline (91.376 us; speedup 1.0000x reference)
//
#include <hip/hip_runtime.h>
#include <cfloat>

#define BLOCK 256
#define RPT 8            // rows per thread -> 2048 rows per block
#define SLICES 64        // column slices per side

typedef float v2f __attribute__((ext_vector_type(2)));

// blockIdx.z==0: rows=A (true), cols=B (pred)  -> sbuf[0]  ("mins")
// blockIdx.z==1: rows=B (pred), cols=A (true)  -> sbuf[1]  ("mins_seeds")
// Minimize s = ||y||^2/2 - x.y ; d2 = ||x||^2 + 2s reconstructed in finalize.
// v2f lanes = 2 COLUMNS (read straight from SoA LDS, no loop-variant splats);
// row constants pre-splatted once. Row-min via fminf(fminf(..)) -> v_min3_f32.
// Inner cost: 3 v_pk_fma_f32 + 1 v_min3_f32 per row per col-pair = 2.0 inst/pair.
__global__ __launch_bounds__(BLOCK) void pairmin_kernel(
    const float* __restrict__ A, const float* __restrict__ B,
    float* __restrict__ hdr, float* __restrict__ sbuf,
    int n, int m, int colsPerSlice, int strideRows)
{
    // zero the scalar-accumulator header (visible to finalize via kernel boundary)
    if (blockIdx.x == 0 && blockIdx.y == 0 && blockIdx.z == 0 && threadIdx.x < 8)
        hdr[threadIdx.x] = 0.f;

    const float* X; const float* Y; int nx_, ny_;
    float* out_slice;
    if (blockIdx.z == 0) { X = A; Y = B; nx_ = n; ny_ = m; out_slice = sbuf; }
    else                 { X = B; Y = A; nx_ = m; ny_ = n;
                           out_slice = sbuf + (size_t)SLICES * strideRows; }
    out_slice += (size_t)blockIdx.y * strideRows;

    const int tid = threadIdx.x;
    const int rowBase = blockIdx.x * (BLOCK * RPT);
    if (rowBase >= nx_) return;                      // block-uniform exit

    const int colBeg = blockIdx.y * colsPerSlice;
    const int colEnd = min(colBeg + colsPerSlice, ny_);

    // Loop-invariant splatted row constants (negated), scalar min accumulators.
    v2f nrx[RPT], nry[RPT], nrz[RPT];
    float mn[RPT];
#pragma unroll
    for (int k = 0; k < RPT; ++k) {
        const int r = rowBase + tid + k * BLOCK;
        const int rr = (r < nx_) ? r : 0;
        const float x = -X[3 * rr + 0];
        const float y = -X[3 * rr + 1];
        const float z = -X[3 * rr + 2];
        nrx[k] = (v2f){x, x};
        nry[k] = (v2f){y, y};
        nrz[k] = (v2f){z, z};
        mn[k] = FLT_MAX;
    }

    __shared__ float ldsx[BLOCK], ldsy[BLOCK], ldsz[BLOCK], ldsw[BLOCK];

    for (int c0 = colBeg; c0 < colEnd; c0 += BLOCK) {
        const int cnt = min(BLOCK, colEnd - c0);
        if (tid < cnt) {
            const int c = c0 + tid;
            const float yx = Y[3 * c + 0];
            const float yy = Y[3 * c + 1];
            const float yz = Y[3 * c + 2];
            ldsx[tid] = yx; ldsy[tid] = yy; ldsz[tid] = yz;
            ldsw[tid] = 0.5f * fmaf(yx, yx, fmaf(yy, yy, yz * yz));
        }
        __syncthreads();

        const int pairs = cnt >> 1;
#pragma unroll 2
        for (int jj = 0; jj < pairs; ++jj) {
            const v2f cx = *(const v2f*)&ldsx[2 * jj];   // ds_read_b64, broadcast
            const v2f cy = *(const v2f*)&ldsy[2 * jj];
            const v2f cz = *(const v2f*)&ldsz[2 * jj];
            const v2f cw = *(const v2f*)&ldsw[2 * jj];
#pragma unroll
            for (int k = 0; k < RPT; ++k) {
                v2f s = __builtin_elementwise_fma(nrz[k], cz, cw);
                s = __builtin_elementwise_fma(nry[k], cy, s);
                s = __builtin_elementwise_fma(nrx[k], cx, s);
                mn[k] = fminf(fminf(mn[k], s.x), s.y);   // -> v_min3_f32
            }
        }
        if (cnt & 1) {                                   // odd-count tail col
            const int j = cnt - 1;
            const float cx = ldsx[j], cy = ldsy[j], cz = ldsz[j], cw = ldsw[j];
#pragma unroll
            for (int k = 0; k < RPT; ++k) {
                float s = fmaf(nrz[k].x, cz, cw);
                s = fmaf(nry[k].x, cy, s);
                s = fmaf(nrx[k].x, cx, s);
                mn[k] = fminf(mn[k], s);
            }
        }
        __syncthreads();
    }

#pragma unroll
    for (int k = 0; k < RPT; ++k) {
        const int r = rowBase + tid + k * BLOCK;
        if (r < nx_) out_slice[r] = mn[k];
    }
}

// One row of each side per thread. ws header: hdr[0]=sumA, hdr[1]=sumB,
// hdr[2]=ticket. out layout: [loss+loss_seeds, mins_seeds(m), loss, loss_seeds]
__global__ __launch_bounds__(256) void finalize_kernel(
    const float* __restrict__ A, const float* __restrict__ B,
    const float* __restrict__ sbuf, float* __restrict__ hdr,
    float* __restrict__ out, int n, int m, int strideRows)
{
    const int i = blockIdx.x * 256 + threadIdx.x;
    float sa = 0.f, sb = 0.f;
    if (i < n) {
        float s = FLT_MAX;
        const float* p = sbuf + i;
#pragma unroll 8
        for (int k = 0; k < SLICES; ++k) s = fminf(s, p[(size_t)k * strideRows]);
        const float ax = A[3 * i], ay = A[3 * i + 1], az = A[3 * i + 2];
        const float nrm = fmaf(ax, ax, fmaf(ay, ay, az * az));
        sa = sqrtf(fmaxf(fmaf(2.f, s, nrm), 0.f));
    }
    if (i < m) {
        float s = FLT_MAX;
        const float* p = sbuf + (size_t)SLICES * strideRows + i;
#pragma unroll 8
        for (int k = 0; k < SLICES; ++k) s = fminf(s, p[(size_t)k * strideRows]);
        const float bx = B[3 * i], by = B[3 * i + 1], bz = B[3 * i + 2];
        const float nrm = fmaf(bx, bx, fmaf(by, by, bz * bz));
        const float v = sqrtf(fmaxf(fmaf(2.f, s, nrm), 0.f));
        out[1 + i] = v;                  // mins_seeds
        sb = v;
    }

#pragma unroll
    for (int off = 32; off > 0; off >>= 1) {
        sa += __shfl_down(sa, off, 64);
        sb += __shfl_down(sb, off, 64);
    }
    __shared__ float reda[4], redb[4];
    const int wave = threadIdx.x >> 6;
    const int lane = threadIdx.x & 63;
    if (lane == 0) { reda[wave] = sa; redb[wave] = sb; }
    __syncthreads();

    if (threadIdx.x == 0) {
        const float ta = reda[0] + reda[1] + reda[2] + reda[3];
        const float tb = redb[0] + redb[1] + redb[2] + redb[3];
        atomicAdd(&hdr[0], ta);
        atomicAdd(&hdr[1], tb);
        __threadfence();
        const unsigned ticket = atomicAdd((unsigned*)&hdr[2], 1u);
        if (ticket == (unsigned)(gridDim.x - 1)) {
            const float fa = atomicAdd(&hdr[0], 0.f);   // coherent read of totals
            const float fb = atomicAdd(&hdr[1], 0.f);
            const float loss = fa / (float)n;
            const float loss_seeds = fb / (float)m;
            out[0] = loss + loss_seeds;
            out[1 + m] = loss;
            out[2 + m] = loss_seeds;
        }
    }
}

extern "C" void kernel_launch(void* const* d_in, const int* in_sizes, int n_in,
                              void* d_out, int out_size, void* d_ws, size_t ws_size,
                              hipStream_t stream) {
    const int n = in_sizes[0] / 3;   // true_pos count
    const int m = in_sizes[1] / 3;   // pred_pos count
    const float* A = (const float*)d_in[0];
    const float* B = (const float*)d_in[1];
    float* out = (float*)d_out;

    float* hdr = (float*)d_ws;                        // 64-byte header region
    float* sbuf = (float*)((char*)d_ws + 64);         // 2*SLICES*maxnm floats

    const int maxnm = (n > m) ? n : m;
    const int gx = (maxnm + BLOCK * RPT - 1) / (BLOCK * RPT);
    const int colsPerSlice = (maxnm + SLICES - 1) / SLICES;
    dim3 grid(gx, SLICES, 2);
    pairmin_kernel<<<grid, BLOCK, 0, stream>>>(A, B, hdr, sbuf, n, m,
                                               colsPerSlice, maxnm);

    const int fb = (maxnm + 255) / 256;
    finalize_kernel<<<fb, 256, 0, stream>>>(A, B, sbuf, hdr, out, n, m, maxnm);
}